// Round 6
// baseline (720.356 us; speedup 1.0000x reference)
//
#include <hip/hip_runtime.h>
#include <math.h>

#define C_   128
#define HU_  128
#define WU_  192
#define HD_  64
#define WD_  96
#define HWD_ (HD_ * WD_)

typedef unsigned short u16;
typedef __attribute__((ext_vector_type(8))) short s8v;   // 8 bf16 = 4 VGPRs
typedef __attribute__((ext_vector_type(4))) float f4v;   // MFMA C/D

// ---- workspace layout (u16 units) ----
#define OFF_Q   0        // 2 layers x 16384
#define OFF_K   32768
#define OFF_V   65536
#define OFF_O   98304
#define OFF_F1  131072   // 2 layers x 65536
#define OFF_F2  262144
#define OFF_XC  393216   // 49152 (out1 Wa+Wc, 128x384)
#define OFF_CC  442368   // 49152 (out1 Wb-Wc, 128x384)
#define OFF_NRM 491520   // normalized ctx bf16: (B,HD,WD,C) = 1572864 u16
// total 2064384 u16 ≈ 4.0 MB

#define SLOT 2176        // u16 per LDS tile slot (16 rows x 136)

__device__ __forceinline__ u16 f2bf(float f) {
    unsigned u = __float_as_uint(f);
    unsigned r = (u + 0x7FFFu + ((u >> 16) & 1u)) >> 16;   // RNE
    return (u16)r;
}
__device__ __forceinline__ float bfu(u16 h) { return __uint_as_float(((unsigned)h) << 16); }

// tanh-gelu via fast exp: tanh(y) = 1 - 2/(1+e^{2y})
__device__ __forceinline__ float gelu_tanh(float x) {
    float u = 1.5957691216057308f * (x + 0.044715f * x * x * x);  // 2*sqrt(2/pi)*inner
    float e = __expf(u);
    float th = 1.0f - 2.0f / (1.0f + e);
    return 0.5f * x * (1.0f + th);
}
// exact-gelu via A&S 7.1.26 erf (max err 1.5e-7)
__device__ __forceinline__ float fast_erf(float x) {
    float z = fabsf(x);
    float t = 1.0f / (1.0f + 0.3275911f * z);
    float p = t * (0.254829592f + t * (-0.284496736f + t * (1.421413741f +
              t * (-1.453152027f + t * 1.061405429f))));
    float r = 1.0f - p * __expf(-z * z);
    return copysignf(r, x);
}
__device__ __forceinline__ float gelu_erf(float x) {
    return 0.5f * x * (1.0f + fast_erf(x * 0.7071067811865476f));
}

// ---------------- prologue 1: all weight swizzles in one kernel ----------------
// frag (kt,nt): 64 lanes x 8 bf16; elem j = W[kt*32+8*(lane>>4)+j][nt*16+(lane&15)]
// 960 frags total; 4 frags per 256-thread block -> 240 blocks.
__global__ __launch_bounds__(256) void swz_all(
    const float* __restrict__ q_w, const float* __restrict__ k_w,
    const float* __restrict__ v_w, const float* __restrict__ o_w,
    const float* __restrict__ f1w, const float* __restrict__ f2w,
    const float* __restrict__ o1w, u16* __restrict__ ws)
{
    int tid = blockIdx.x * 256 + threadIdx.x;
    int f = tid >> 6, lane = tid & 63;
    int rq = 8 * (lane >> 4), cq = lane & 15;
    const float* src; const float* src2 = nullptr; float sgn = 1.f;
    int NT, N, dstoff, lf;
    if (f < 64)       { src = q_w;  NT = 8;  N = 128; dstoff = OFF_Q;  lf = f; }
    else if (f < 128) { src = k_w;  NT = 8;  N = 128; dstoff = OFF_K;  lf = f - 64; }
    else if (f < 192) { src = v_w;  NT = 8;  N = 128; dstoff = OFF_V;  lf = f - 128; }
    else if (f < 256) { src = o_w;  NT = 8;  N = 128; dstoff = OFF_O;  lf = f - 192; }
    else if (f < 512) { src = f1w;  NT = 32; N = 512; dstoff = OFF_F1; lf = f - 256; }
    else if (f < 768) { src = f2w;  NT = 8;  N = 128; dstoff = OFF_F2; lf = f - 512; }
    else if (f < 864) { src = o1w;             src2 = o1w + 256 * 384; sgn =  1.f;
                        NT = 24; N = 384; dstoff = OFF_XC; lf = f - 768; }
    else              { src = o1w + 128 * 384; src2 = o1w + 256 * 384; sgn = -1.f;
                        NT = 24; N = 384; dstoff = OFF_CC; lf = f - 864; }
    int kt = lf / NT, nt = lf - kt * NT;
    int row0 = kt * 32 + rq, col = nt * 16 + cq;
    s8v o;
#pragma unroll
    for (int j = 0; j < 8; ++j) {
        float v = src[(size_t)(row0 + j) * N + col];
        if (src2) v += sgn * src2[(size_t)(row0 + j) * N + col];
        o[j] = (short)f2bf(v);
    }
    *(s8v*)(ws + dstoff + (size_t)lf * 512 + (size_t)lane * 8) = o;
}

// ---------------- prologue 2: per-down-pixel LN of feat_map ----------------
// nrm[((b*HD+y)*WD+x)*128 + c] = LN(feat_map[b,:,y,x]) (eps 1e-5), bf16
__global__ __launch_bounds__(256) void norm_kernel(const float* __restrict__ fm,
                                                   u16* __restrict__ dst) {
    int row = blockIdx.x;          // b*HD + y
    int b = row >> 6, y = row & 63;
    __shared__ float tile[128 * 97];
    __shared__ float smean[96], srst[96];
    for (int idx = threadIdx.x; idx < 128 * 96; idx += 256) {
        int c = idx / 96, w = idx - c * 96;
        tile[c * 97 + w] = fm[(((size_t)b * 128 + c) * 64 + y) * 96 + w];
    }
    __syncthreads();
    if (threadIdx.x < 96) {
        int w = threadIdx.x;
        float s = 0.f, ss = 0.f;
        for (int c = 0; c < 128; ++c) { float v = tile[c * 97 + w]; s += v; ss += v * v; }
        float mn = s * (1.f / 128.f);
        smean[w] = mn;
        srst[w]  = rsqrtf(ss * (1.f / 128.f) - mn * mn + 1e-5f);
    }
    __syncthreads();
    for (int idx = threadIdx.x; idx < 96 * 16; idx += 256) {
        int w = idx >> 4, cg = idx & 15;
        float mn = smean[w], iv = srst[w];
        s8v o;
#pragma unroll
        for (int j = 0; j < 8; ++j)
            o[j] = (short)f2bf((tile[(8 * cg + j) * 97 + w] - mn) * iv);
        *(s8v*)(dst + ((size_t)row * 96 + w) * 128 + 8 * cg) = o;
    }
}

// ---------------- main fused kernel: 1 wave = 16 pixels ----------------
__global__ __launch_bounds__(64, 2) void fused_kernel(
    const u16*  __restrict__ nrmb, const float* __restrict__ fmu,
    const u16*  __restrict__ wsb,
    const float* __restrict__ ctx_g, const float* __restrict__ ctx_b,
    const float* __restrict__ qb, const float* __restrict__ kb,
    const float* __restrict__ vb, const float* __restrict__ ob,
    const float* __restrict__ f1b, const float* __restrict__ f2b,
    const float* __restrict__ o1b, const float* __restrict__ o2w,
    const float* __restrict__ o2b,
    float* __restrict__ out)
{
    const int lane = threadIdx.x;
    const int cidx = lane & 15, quad = lane >> 4;
    const int n0 = blockIdx.x * 16;
    const int b  = n0 / (HU_ * WU_);
    const int rem = n0 - b * (HU_ * WU_);
    const int hu  = rem / WU_;
    const int wu0 = rem - hu * WU_;

    __shared__ u16 arena[4 * SLOT];     // 17408 B: slot0 xn/hn/xf, slots1-2 q|xfb, slot3 oT; sH = slots0-3
    __shared__ float s_at[272];         // 1088 B: scores / s_rs
    u16*   sH   = arena;                          // stride 520
    float* bufQ = (float*)(arena + SLOT);         // stride 136 f32 (slots 1-2)
    float* xfb  = (float*)(arena + SLOT);         // stride 97 f32 (head)
    float* s_rs = s_at;

    // residual x: row p = 4*quad+r, ch = 16*nt+cidx
    float xacc[8][4];
#pragma unroll
    for (int nt = 0; nt < 8; ++nt) {
        int ch = 16 * nt + cidx;
        const float* p = fmu + ((size_t)(b * C_ + ch) * HU_ + hu) * WU_ + wu0 + 4 * quad;
#pragma unroll
        for (int r = 0; r < 4; ++r) xacc[nt][r] = p[r];
    }

    const float slopes[4] = {0.451801007f, 0.204124145f, 0.092223264f, 0.041666668f};
    const int ry0 = min(hu >> 1, HD_ - 1);
    const int ry1 = min((hu >> 1) + 1, HD_ - 1);
    const float dyv0 = -(float)abs(hu - 2 * ry0);
    const float dyv1 = -(float)abs(hu - 2 * ry1);

    // per-lane ctx pixel row base: row m = 4*plocal + k2; plocal=cidx>>2, k2=cidx&3
    const int k2l = cidx & 3;
    const int ryl = (k2l >> 1) ? ry1 : ry0;
    int cbase[4];
#pragma unroll
    for (int mt = 0; mt < 4; ++mt) {
        int p = 4 * mt + (cidx >> 2);
        int rxv = min(((wu0 + p) >> 1) + (k2l & 1), WD_ - 1);
        cbase[mt] = ((b * HD_ + ryl) * WD_ + rxv) * 128;
    }

#pragma unroll 1
    for (int ly = 0; ly < 2; ++ly) {
        const u16* Wq = wsb + OFF_Q  + ly * 16384;
        const u16* Wk = wsb + OFF_K  + ly * 16384;
        const u16* Wv = wsb + OFF_V  + ly * 16384;
        const u16* Wo = wsb + OFF_O  + ly * 16384;
        const u16* W1 = wsb + OFF_F1 + ly * 65536;
        const u16* W2 = wsb + OFF_F2 + ly * 65536;
        const float* gv = ctx_g + ly * C_;
        const float* bv = ctx_b + ly * C_;

        // ---- xn = LN(x,1e-6) -> slot0 ----
        {
            float mo[4], io[4];
#pragma unroll
            for (int r = 0; r < 4; ++r) {
                float s = 0.f, ss = 0.f;
#pragma unroll
                for (int nt = 0; nt < 8; ++nt) { float v = xacc[nt][r]; s += v; ss += v * v; }
#pragma unroll
                for (int m = 1; m <= 8; m <<= 1) { s += __shfl_xor(s, m, 64); ss += __shfl_xor(ss, m, 64); }
                float mn = s * (1.f / 128.f);
                mo[r] = mn; io[r] = rsqrtf(ss * (1.f / 128.f) - mn * mn + 1e-6f);
            }
#pragma unroll
            for (int nt = 0; nt < 8; ++nt)
#pragma unroll
                for (int r = 0; r < 4; ++r)
                    arena[(4 * quad + r) * 136 + 16 * nt + cidx] =
                        f2bf((xacc[nt][r] - mo[r]) * io[r]);
        }
        __syncthreads();

        // ---- q = xn @ Wq + qb -> bufQ (f32, slots1-2) ----
        {
            s8v a_xn[4];
#pragma unroll
            for (int kt = 0; kt < 4; ++kt)
                a_xn[kt] = *(const s8v*)(arena + cidx * 136 + kt * 32 + 8 * quad);
            f4v qa[8];
#pragma unroll
            for (int nt = 0; nt < 8; ++nt) {
                float bvv = qb[ly * C_ + 16 * nt + cidx];
                f4v t = {bvv, bvv, bvv, bvv}; qa[nt] = t;
            }
#pragma unroll
            for (int kt = 0; kt < 4; ++kt)
#pragma unroll
                for (int nt = 0; nt < 8; ++nt) {
                    s8v w = *(const s8v*)(Wq + ((size_t)((kt * 8 + nt) * 64 + lane)) * 8);
                    qa[nt] = __builtin_amdgcn_mfma_f32_16x16x32_bf16(a_xn[kt], w, qa[nt], 0, 0, 0);
                }
#pragma unroll
            for (int nt = 0; nt < 8; ++nt)
#pragma unroll
                for (int r = 0; r < 4; ++r)
                    bufQ[(4 * quad + r) * 136 + 16 * nt + cidx] = qa[nt][r];
        }
        __syncthreads();

        // ---- cn A-frags direct from nrmb (+affine in regs), held through k and v ----
        s8v a_cn[4][4];
#pragma unroll
        for (int kt = 0; kt < 4; ++kt) {
            int co = 32 * kt + 8 * quad;
            float4 g0 = *(const float4*)&gv[co], g1 = *(const float4*)&gv[co + 4];
            float4 b0 = *(const float4*)&bv[co], b1 = *(const float4*)&bv[co + 4];
#pragma unroll
            for (int mt = 0; mt < 4; ++mt) {
                s8v raw = *(const s8v*)(nrmb + cbase[mt] + co);
                s8v o;
                o[0] = (short)f2bf(fmaf(bfu((u16)raw[0]), g0.x, b0.x));
                o[1] = (short)f2bf(fmaf(bfu((u16)raw[1]), g0.y, b0.y));
                o[2] = (short)f2bf(fmaf(bfu((u16)raw[2]), g0.z, b0.z));
                o[3] = (short)f2bf(fmaf(bfu((u16)raw[3]), g0.w, b0.w));
                o[4] = (short)f2bf(fmaf(bfu((u16)raw[4]), g1.x, b1.x));
                o[5] = (short)f2bf(fmaf(bfu((u16)raw[5]), g1.y, b1.y));
                o[6] = (short)f2bf(fmaf(bfu((u16)raw[6]), g1.z, b1.z));
                o[7] = (short)f2bf(fmaf(bfu((u16)raw[7]), g1.w, b1.w));
                a_cn[kt][mt] = o;
            }
        }

        // ---- k GEMM (frag-once) + fused raw scores -> s_at ----
#pragma unroll 1
        for (int h = 0; h < 4; ++h) {
            f4v ka[2][4];
#pragma unroll
            for (int ntp = 0; ntp < 2; ++ntp) {
                float kbb = kb[ly * C_ + 16 * (2 * h + ntp) + cidx];
#pragma unroll
                for (int mt = 0; mt < 4; ++mt) { f4v t = {kbb, kbb, kbb, kbb}; ka[ntp][mt] = t; }
            }
#pragma unroll
            for (int kt = 0; kt < 4; ++kt)
#pragma unroll
                for (int ntp = 0; ntp < 2; ++ntp) {
                    int nt = 2 * h + ntp;
                    s8v w = *(const s8v*)(Wk + ((size_t)((kt * 8 + nt) * 64 + lane)) * 8);
#pragma unroll
                    for (int mt = 0; mt < 4; ++mt)
                        ka[ntp][mt] = __builtin_amdgcn_mfma_f32_16x16x32_bf16(a_cn[kt][mt], w, ka[ntp][mt], 0, 0, 0);
                }
            float part[4][4];
#pragma unroll
            for (int mt = 0; mt < 4; ++mt)
#pragma unroll
                for (int r = 0; r < 4; ++r) part[mt][r] = 0.f;
#pragma unroll
            for (int ntp = 0; ntp < 2; ++ntp)
#pragma unroll
                for (int mt = 0; mt < 4; ++mt) {
                    float qv = bufQ[(4 * mt + quad) * 136 + 16 * (2 * h + ntp) + cidx];
#pragma unroll
                    for (int r = 0; r < 4; ++r) part[mt][r] = fmaf(qv, ka[ntp][mt][r], part[mt][r]);
                }
#pragma unroll
            for (int mt = 0; mt < 4; ++mt)
#pragma unroll
                for (int r = 0; r < 4; ++r) {
#pragma unroll
                    for (int m = 1; m <= 8; m <<= 1) part[mt][r] += __shfl_xor(part[mt][r], m, 64);
                }
            if (cidx == 0) {
#pragma unroll
                for (int mt = 0; mt < 4; ++mt) {
                    float4 t = {part[mt][0], part[mt][1], part[mt][2], part[mt][3]};
                    *(float4*)&s_at[(4 * mt + quad) * 16 + 4 * h] = t;
                }
            }
        }
        __syncthreads();

        // ---- softmax in place (lane = p*4+h; reads/writes its own 4 floats) ----
        {
            int p = lane >> 2, h = lane & 3;
            float4 sc = *(float4*)&s_at[p * 16 + 4 * h];
            int pw = wu0 + p;
            float sim[4] = {sc.x, sc.y, sc.z, sc.w};
#pragma unroll
            for (int r = 0; r < 4; ++r) {
                int rxv = min((pw >> 1) + (r & 1), WD_ - 1);
                float cd = ((r >> 1) ? dyv1 : dyv0) - (float)abs(pw - 2 * rxv);
                sim[r] = sim[r] * 0.17677669529663687f + slopes[h] * cd;
            }
            float mx = fmaxf(fmaxf(sim[0], sim[1]), fmaxf(sim[2], sim[3]));
            float e0 = __expf(sim[0] - mx), e1 = __expf(sim[1] - mx);
            float e2 = __expf(sim[2] - mx), e3 = __expf(sim[3] - mx);
            float si = 1.f / (e0 + e1 + e2 + e3);
            float4 at = {e0 * si, e1 * si, e2 * si, e3 * si};
            *(float4*)&s_at[p * 16 + 4 * h] = at;
        }
        __syncthreads();

        // ---- v GEMM (frag-once) + fused o = attn@v -> oT (slot3) ----
#pragma unroll 1
        for (int nt = 0; nt < 8; ++nt) {
            f4v va[4];
            float vbb = vb[ly * C_ + 16 * nt + cidx];
#pragma unroll
            for (int mt = 0; mt < 4; ++mt) { f4v t = {vbb, vbb, vbb, vbb}; va[mt] = t; }
#pragma unroll
            for (int kt = 0; kt < 4; ++kt) {
                s8v w = *(const s8v*)(Wv + ((size_t)((kt * 8 + nt) * 64 + lane)) * 8);
#pragma unroll
                for (int mt = 0; mt < 4; ++mt)
                    va[mt] = __builtin_amdgcn_mfma_f32_16x16x32_bf16(a_cn[kt][mt], w, va[mt], 0, 0, 0);
            }
            int h = nt >> 1;
#pragma unroll
            for (int mt = 0; mt < 4; ++mt) {
                float4 at = *(float4*)&s_at[(4 * mt + quad) * 16 + 4 * h];
                float ov = at.x * va[mt][0] + at.y * va[mt][1] + at.z * va[mt][2] + at.w * va[mt][3];
                arena[3 * SLOT + (4 * mt + quad) * 136 + 16 * nt + cidx] = f2bf(ov);
            }
        }
        __syncthreads();

        // ---- x += o @ Wo + ob ----
        {
            s8v a_o[4];
#pragma unroll
            for (int kt = 0; kt < 4; ++kt)
                a_o[kt] = *(const s8v*)(arena + 3 * SLOT + cidx * 136 + kt * 32 + 8 * quad);
            f4v oa[8];
#pragma unroll
            for (int nt = 0; nt < 8; ++nt) {
                float bvv = ob[ly * C_ + 16 * nt + cidx];
                f4v t = {bvv, bvv, bvv, bvv}; oa[nt] = t;
            }
#pragma unroll
            for (int kt = 0; kt < 4; ++kt)
#pragma unroll
                for (int nt = 0; nt < 8; ++nt) {
                    s8v w = *(const s8v*)(Wo + ((size_t)((kt * 8 + nt) * 64 + lane)) * 8);
                    oa[nt] = __builtin_amdgcn_mfma_f32_16x16x32_bf16(a_o[kt], w, oa[nt], 0, 0, 0);
                }
#pragma unroll
            for (int nt = 0; nt < 8; ++nt)
#pragma unroll
                for (int r = 0; r < 4; ++r) xacc[nt][r] += oa[nt][r];
        }
        __syncthreads();

        // ---- hn = LN(x,1e-6) -> slot0 ----
        {
            float mo[4], io[4];
#pragma unroll
            for (int r = 0; r < 4; ++r) {
                float s = 0.f, ss = 0.f;
#pragma unroll
                for (int nt = 0; nt < 8; ++nt) { float v = xacc[nt][r]; s += v; ss += v * v; }
#pragma unroll
                for (int m = 1; m <= 8; m <<= 1) { s += __shfl_xor(s, m, 64); ss += __shfl_xor(ss, m, 64); }
                float mn = s * (1.f / 128.f);
                mo[r] = mn; io[r] = rsqrtf(ss * (1.f / 128.f) - mn * mn + 1e-6f);
            }
#pragma unroll
            for (int nt = 0; nt < 8; ++nt)
#pragma unroll
                for (int r = 0; r < 4; ++r)
                    arena[(4 * quad + r) * 136 + 16 * nt + cidx] =
                        f2bf((xacc[nt][r] - mo[r]) * io[r]);
        }
        __syncthreads();

        // ---- preload hn A-frags, then fc1 writes sH over slots0-3 ----
        s8v a_hn[4];
#pragma unroll
        for (int kt = 0; kt < 4; ++kt)
            a_hn[kt] = *(const s8v*)(arena + cidx * 136 + kt * 32 + 8 * quad);
        __syncthreads();

        // ---- fc1 (128->512) + gelu_tanh -> sH (stride 520) ----
#pragma unroll 1
        for (int half = 0; half < 2; ++half) {
            f4v fa[16];
#pragma unroll
            for (int nt = 0; nt < 16; ++nt) {
                float bvv = f1b[ly * 512 + 16 * (half * 16 + nt) + cidx];
                f4v t = {bvv, bvv, bvv, bvv}; fa[nt] = t;
            }
#pragma unroll
            for (int kt = 0; kt < 4; ++kt)
#pragma unroll
                for (int nt = 0; nt < 16; ++nt) {
                    int ntg = half * 16 + nt;
                    s8v w = *(const s8v*)(W1 + ((size_t)((kt * 32 + ntg) * 64 + lane)) * 8);
                    fa[nt] = __builtin_amdgcn_mfma_f32_16x16x32_bf16(a_hn[kt], w, fa[nt], 0, 0, 0);
                }
#pragma unroll
            for (int nt = 0; nt < 16; ++nt)
#pragma unroll
                for (int r = 0; r < 4; ++r)
                    sH[(4 * quad + r) * 520 + 16 * (half * 16 + nt) + cidx] =
                        f2bf(gelu_tanh(fa[nt][r]));
        }
        __syncthreads();

        // ---- x += act @ W2 + f2b ----
        {
            f4v ga[8];
#pragma unroll
            for (int nt = 0; nt < 8; ++nt) {
                float bvv = f2b[ly * C_ + 16 * nt + cidx];
                f4v t = {bvv, bvv, bvv, bvv}; ga[nt] = t;
            }
            for (int kt = 0; kt < 16; ++kt) {
                s8v a = *(const s8v*)(sH + cidx * 520 + kt * 32 + 8 * quad);
#pragma unroll
                for (int nt = 0; nt < 8; ++nt) {
                    s8v w = *(const s8v*)(W2 + ((size_t)((kt * 8 + nt) * 64 + lane)) * 8);
                    ga[nt] = __builtin_amdgcn_mfma_f32_16x16x32_bf16(a, w, ga[nt], 0, 0, 0);
                }
            }
#pragma unroll
            for (int nt = 0; nt < 8; ++nt)
#pragma unroll
                for (int r = 0; r < 4; ++r) xacc[nt][r] += ga[nt][r];
        }
        __syncthreads();
    } // layer loop

    // ================= head =================
    // xf = LN(x,1e-6) -> slot0 (bf16 tile)
    {
        float mo[4], io[4];
#pragma unroll
        for (int r = 0; r < 4; ++r) {
            float s = 0.f, ss = 0.f;
#pragma unroll
            for (int nt = 0; nt < 8; ++nt) { float v = xacc[nt][r]; s += v; ss += v * v; }
#pragma unroll
            for (int m = 1; m <= 8; m <<= 1) { s += __shfl_xor(s, m, 64); ss += __shfl_xor(ss, m, 64); }
            float mn = s * (1.f / 128.f);
            mo[r] = mn; io[r] = rsqrtf(ss * (1.f / 128.f) - mn * mn + 1e-6f);
        }
#pragma unroll
        for (int nt = 0; nt < 8; ++nt)
#pragma unroll
            for (int r = 0; r < 4; ++r)
                arena[(4 * quad + r) * 136 + 16 * nt + cidx] =
                    f2bf((xacc[nt][r] - mo[r]) * io[r]);
    }
    __syncthreads();

    s8v a_xf[4];
#pragma unroll
    for (int kt = 0; kt < 4; ++kt)
        a_xf[kt] = *(const s8v*)(arena + cidx * 136 + kt * 32 + 8 * quad);

    // cf A-frags direct from nrmb (raw, already bf16)
    s8v a_cf[4][4];
#pragma unroll
    for (int kt = 0; kt < 4; ++kt)
#pragma unroll
        for (int mt = 0; mt < 4; ++mt)
            a_cf[kt][mt] = *(const s8v*)(nrmb + cbase[mt] + 32 * kt + 8 * quad);

    const u16* Wxc = wsb + OFF_XC;
    const u16* Wcc = wsb + OFF_CC;
    float part[4][4];
#pragma unroll
    for (int mt = 0; mt < 4; ++mt)
#pragma unroll
        for (int r = 0; r < 4; ++r) part[mt][r] = 0.f;

#pragma unroll 1
    for (int ntc = 0; ntc < 4; ++ntc) {
        // xf-part chunk (includes out1 bias) -> xfb
        {
            f4v hx[6];
#pragma unroll
            for (int ntl = 0; ntl < 6; ++ntl) {
                float hb = o1b[16 * (6 * ntc + ntl) + cidx];
                f4v t = {hb, hb, hb, hb}; hx[ntl] = t;
            }
#pragma unroll
            for (int kt = 0; kt < 4; ++kt)
#pragma unroll
                for (int ntl = 0; ntl < 6; ++ntl) {
                    s8v w = *(const s8v*)(Wxc + ((size_t)((kt * 24 + 6 * ntc + ntl) * 64 + lane)) * 8);
                    hx[ntl] = __builtin_amdgcn_mfma_f32_16x16x32_bf16(a_xf[kt], w, hx[ntl], 0, 0, 0);
                }
#pragma unroll
            for (int ntl = 0; ntl < 6; ++ntl)
#pragma unroll
                for (int r = 0; r < 4; ++r)
                    xfb[(4 * quad + r) * 97 + 16 * ntl + cidx] = hx[ntl][r];
        }
        __syncthreads();

        // cf-part chunk, all 4 M-tiles (frag-once)
        f4v hc[6][4];
#pragma unroll
        for (int ntl = 0; ntl < 6; ++ntl)
#pragma unroll
            for (int mt = 0; mt < 4; ++mt) { f4v t = {0.f, 0.f, 0.f, 0.f}; hc[ntl][mt] = t; }
#pragma unroll
        for (int kt = 0; kt < 4; ++kt)
#pragma unroll
            for (int ntl = 0; ntl < 6; ++ntl) {
                s8v w = *(const s8v*)(Wcc + ((size_t)((kt * 24 + 6 * ntc + ntl) * 64 + lane)) * 8);
#pragma unroll
                for (int mt = 0; mt < 4; ++mt)
                    hc[ntl][mt] = __builtin_amdgcn_mfma_f32_16x16x32_bf16(a_cf[kt][mt], w, hc[ntl][mt], 0, 0, 0);
            }

        // epilogue: h1 = gelu_erf(cf-part + xf-part); accumulate out2 dot
#pragma unroll
        for (int ntl = 0; ntl < 6; ++ntl) {
            float w2v = o2w[16 * (6 * ntc + ntl) + cidx];
#pragma unroll
            for (int mt = 0; mt < 4; ++mt)
#pragma unroll
                for (int r = 0; r < 4; ++r) {
                    float h1 = hc[ntl][mt][r] + xfb[(4 * mt + quad) * 97 + 16 * ntl + cidx];
                    part[mt][r] = fmaf(gelu_erf(h1), w2v, part[mt][r]);
                }
        }
        __syncthreads();
    }

    // reduce over 16 cidx lanes, + out2 bias
#pragma unroll
    for (int mt = 0; mt < 4; ++mt)
#pragma unroll
        for (int r = 0; r < 4; ++r) {
#pragma unroll
            for (int m = 1; m <= 8; m <<= 1) part[mt][r] += __shfl_xor(part[mt][r], m, 64);
            part[mt][r] += o2b[0];
        }
    if (cidx == 0) {
#pragma unroll
        for (int mt = 0; mt < 4; ++mt) {
            float4 t = {part[mt][0], part[mt][1], part[mt][2], part[mt][3]};
            *(float4*)&s_rs[(4 * mt + quad) * 4] = t;
        }
    }
    __syncthreads();

    // final softmax over K2 + store
    if (lane < 16) {
        int p = lane;
        float4 vv = *(float4*)&s_rs[4 * p];
        float mx = fmaxf(fmaxf(vv.x, vv.y), fmaxf(vv.z, vv.w));
        float e0 = __expf(vv.x - mx), e1 = __expf(vv.y - mx);
        float e2 = __expf(vv.z - mx), e3 = __expf(vv.w - mx);
        float si = 1.f / (e0 + e1 + e2 + e3);
        size_t base = ((size_t)(b * 4) * HU_ + hu) * WU_ + wu0 + p;
        out[base]                          = e0 * si;
        out[base + (size_t)HU_ * WU_]      = e1 * si;
        out[base + (size_t)2 * HU_ * WU_]  = e2 * si;
        out[base + (size_t)3 * HU_ * WU_]  = e3 * si;
    }
}

extern "C" void kernel_launch(void* const* d_in, const int* in_sizes, int n_in,
                              void* d_out, int out_size, void* d_ws, size_t ws_size,
                              hipStream_t stream) {
    const float* feat_map    = (const float*)d_in[0];
    const float* feat_map_up = (const float*)d_in[1];
    const float* ctx_ln_b    = (const float*)d_in[2];
    const float* q_w  = (const float*)d_in[3];
    const float* q_b  = (const float*)d_in[4];
    const float* k_w  = (const float*)d_in[5];
    const float* k_b  = (const float*)d_in[6];
    const float* v_w  = (const float*)d_in[7];
    const float* v_b  = (const float*)d_in[8];
    const float* o_w  = (const float*)d_in[9];
    const float* o_b  = (const float*)d_in[10];
    const float* fc1_w = (const float*)d_in[11];
    const float* fc1_b = (const float*)d_in[12];
    const float* fc2_w = (const float*)d_in[13];
    const float* fc2_b = (const float*)d_in[14];
    const float* out1_w = (const float*)d_in[15];
    const float* out1_b = (const float*)d_in[16];
    const float* out2_w = (const float*)d_in[17];
    const float* out2_b = (const float*)d_in[18];
    const float* ctx_ln_g = (const float*)d_in[19];
    float* out = (float*)d_out;
    u16* ws = (u16*)d_ws;

    swz_all<<<240, 256, 0, stream>>>(q_w, k_w, v_w, o_w, fc1_w, fc2_w, out1_w, ws);
    norm_kernel<<<128, 256, 0, stream>>>(feat_map, ws + OFF_NRM);

    fused_kernel<<<3072, 64, 0, stream>>>(
        ws + OFF_NRM, feat_map_up, ws, ctx_ln_g, ctx_ln_b,
        q_b, k_b, v_b, o_b, fc1_b, fc2_b,
        out1_b, out2_w, out2_b, out);
}

// Round 7
// 564.073 us; speedup vs baseline: 1.2771x; 1.2771x over previous
//
#include <hip/hip_runtime.h>
#include <math.h>

#define C_   128
#define HU_  128
#define WU_  192
#define HD_  64
#define WD_  96
#define HWD_ (HD_ * WD_)

typedef unsigned short u16;
typedef __attribute__((ext_vector_type(8))) short s8v;   // 8 bf16 = 4 VGPRs
typedef __attribute__((ext_vector_type(4))) float f4v;   // MFMA C/D

// ---- workspace layout (u16 units) ----
#define OFF_Q   0        // 2 layers x 16384
#define OFF_K   32768
#define OFF_V   65536
#define OFF_O   98304
#define OFF_F1  131072   // 2 layers x 65536
#define OFF_F2  262144
#define OFF_XC  393216   // 49152 (out1 Wa+Wc, 128x384)
#define OFF_CC  442368   // 49152 (out1 Wb-Wc, 128x384)
#define OFF_NRM 491520   // normalized ctx bf16: (B,HD,WD,C) = 1572864 u16

#define SLOT 2176        // u16 per LDS tile slot (16 rows x 136)

__device__ __forceinline__ u16 f2bf(float f) {
    unsigned u = __float_as_uint(f);
    unsigned r = (u + 0x7FFFu + ((u >> 16) & 1u)) >> 16;   // RNE
    return (u16)r;
}
__device__ __forceinline__ float bfu(u16 h) { return __uint_as_float(((unsigned)h) << 16); }

__device__ __forceinline__ float gelu_tanh(float x) {
    float u = 1.5957691216057308f * (x + 0.044715f * x * x * x);
    float e = __expf(u);
    float th = 1.0f - 2.0f / (1.0f + e);
    return 0.5f * x * (1.0f + th);
}
__device__ __forceinline__ float fast_erf(float x) {
    float z = fabsf(x);
    float t = 1.0f / (1.0f + 0.3275911f * z);
    float p = t * (0.254829592f + t * (-0.284496736f + t * (1.421413741f +
              t * (-1.453152027f + t * 1.061405429f))));
    float r = 1.0f - p * __expf(-z * z);
    return copysignf(r, x);
}
__device__ __forceinline__ float gelu_erf(float x) {
    return 0.5f * x * (1.0f + fast_erf(x * 0.7071067811865476f));
}

// ---------------- prologue 1: all weight swizzles (+ out1 folding) ----------------
__global__ __launch_bounds__(256) void swz_all(
    const float* __restrict__ q_w, const float* __restrict__ k_w,
    const float* __restrict__ v_w, const float* __restrict__ o_w,
    const float* __restrict__ f1w, const float* __restrict__ f2w,
    const float* __restrict__ o1w, u16* __restrict__ ws)
{
    int tid = blockIdx.x * 256 + threadIdx.x;
    int f = tid >> 6, lane = tid & 63;
    int rq = 8 * (lane >> 4), cq = lane & 15;
    const float* src; const float* src2 = nullptr; float sgn = 1.f;
    int NT, N, dstoff, lf;
    if (f < 64)       { src = q_w;  NT = 8;  N = 128; dstoff = OFF_Q;  lf = f; }
    else if (f < 128) { src = k_w;  NT = 8;  N = 128; dstoff = OFF_K;  lf = f - 64; }
    else if (f < 192) { src = v_w;  NT = 8;  N = 128; dstoff = OFF_V;  lf = f - 128; }
    else if (f < 256) { src = o_w;  NT = 8;  N = 128; dstoff = OFF_O;  lf = f - 192; }
    else if (f < 512) { src = f1w;  NT = 32; N = 512; dstoff = OFF_F1; lf = f - 256; }
    else if (f < 768) { src = f2w;  NT = 8;  N = 128; dstoff = OFF_F2; lf = f - 512; }
    else if (f < 864) { src = o1w;             src2 = o1w + 256 * 384; sgn =  1.f;
                        NT = 24; N = 384; dstoff = OFF_XC; lf = f - 768; }
    else              { src = o1w + 128 * 384; src2 = o1w + 256 * 384; sgn = -1.f;
                        NT = 24; N = 384; dstoff = OFF_CC; lf = f - 864; }
    int kt = lf / NT, nt = lf - kt * NT;
    int row0 = kt * 32 + rq, col = nt * 16 + cq;
    s8v o;
#pragma unroll
    for (int j = 0; j < 8; ++j) {
        float v = src[(size_t)(row0 + j) * N + col];
        if (src2) v += sgn * src2[(size_t)(row0 + j) * N + col];
        o[j] = (short)f2bf(v);
    }
    *(s8v*)(ws + dstoff + (size_t)lf * 512 + (size_t)lane * 8) = o;
}

// ---------------- prologue 2: per-down-pixel LN of feat_map (eps 1e-5) ----------------
__global__ __launch_bounds__(256) void norm_kernel(const float* __restrict__ fm,
                                                   u16* __restrict__ dst) {
    int row = blockIdx.x;          // b*HD + y
    int b = row >> 6, y = row & 63;
    __shared__ float tile[128 * 97];
    __shared__ float smean[96], srst[96];
    for (int idx = threadIdx.x; idx < 128 * 96; idx += 256) {
        int c = idx / 96, w = idx - c * 96;
        tile[c * 97 + w] = fm[(((size_t)b * 128 + c) * 64 + y) * 96 + w];
    }
    __syncthreads();
    if (threadIdx.x < 96) {
        int w = threadIdx.x;
        float s = 0.f, ss = 0.f;
        for (int c = 0; c < 128; ++c) { float v = tile[c * 97 + w]; s += v; ss += v * v; }
        float mn = s * (1.f / 128.f);
        smean[w] = mn;
        srst[w]  = rsqrtf(ss * (1.f / 128.f) - mn * mn + 1e-5f);
    }
    __syncthreads();
    for (int idx = threadIdx.x; idx < 96 * 16; idx += 256) {
        int w = idx >> 4, cg = idx & 15;
        float mn = smean[w], iv = srst[w];
        s8v o;
#pragma unroll
        for (int j = 0; j < 8; ++j)
            o[j] = (short)f2bf((tile[(8 * cg + j) * 97 + w] - mn) * iv);
        *(s8v*)(dst + ((size_t)row * 96 + w) * 128 + 8 * cg) = o;
    }
}

// ---------------- main fused kernel: 1 wave = 16 pixels ----------------
__global__ __launch_bounds__(64, 2) void fused_kernel(
    const u16*  __restrict__ nrmb, const float* __restrict__ fmu,
    const u16*  __restrict__ wsb,
    const float* __restrict__ ctx_g, const float* __restrict__ ctx_b,
    const float* __restrict__ qb, const float* __restrict__ kb,
    const float* __restrict__ vb, const float* __restrict__ ob,
    const float* __restrict__ f1b, const float* __restrict__ f2b,
    const float* __restrict__ o1b, const float* __restrict__ o2w,
    const float* __restrict__ o2b,
    float* __restrict__ out)
{
    const int lane = threadIdx.x;
    const int cidx = lane & 15, quad = lane >> 4;
    const int n0 = blockIdx.x * 16;
    const int b  = n0 / (HU_ * WU_);
    const int rem = n0 - b * (HU_ * WU_);
    const int hu  = rem / WU_;
    const int wu0 = rem - hu * WU_;

    __shared__ u16 arena[5 * SLOT];     // 21760 B
    __shared__ float s_at[272];         // 1088 B
    u16*   sH   = arena;                // fc1 acts, stride 520 (slots 0-3)
    float* s_rs = s_at;

    // residual x: row p = 4*quad+r, ch = 16*nt+cidx
    float xacc[8][4];
#pragma unroll
    for (int nt = 0; nt < 8; ++nt) {
        int ch = 16 * nt + cidx;
        float4 v = *(const float4*)(fmu + ((size_t)(b * C_ + ch) * HU_ + hu) * WU_ + wu0 + 4 * quad);
        xacc[nt][0] = v.x; xacc[nt][1] = v.y; xacc[nt][2] = v.z; xacc[nt][3] = v.w;
    }

    const float slopes[4] = {0.451801007f, 0.204124145f, 0.092223264f, 0.041666668f};
    const int ry0 = min(hu >> 1, HD_ - 1);
    const int ry1 = min((hu >> 1) + 1, HD_ - 1);
    const float dyv0 = -(float)abs(hu - 2 * ry0);
    const float dyv1 = -(float)abs(hu - 2 * ry1);

    const int k2l = cidx & 3;
    const int ryl = (k2l >> 1) ? ry1 : ry0;
    int cbase[4];
#pragma unroll
    for (int mt = 0; mt < 4; ++mt) {
        int p = 4 * mt + (cidx >> 2);
        int rxv = min(((wu0 + p) >> 1) + (k2l & 1), WD_ - 1);
        cbase[mt] = ((b * HD_ + ryl) * WD_ + rxv) * 128;
    }

#pragma unroll 1
    for (int ly = 0; ly < 2; ++ly) {
        const u16* Wq = wsb + OFF_Q  + ly * 16384;
        const u16* Wk = wsb + OFF_K  + ly * 16384;
        const u16* Wv = wsb + OFF_V  + ly * 16384;
        const u16* Wo = wsb + OFF_O  + ly * 16384;
        const u16* W1 = wsb + OFF_F1 + ly * 65536;
        const u16* W2 = wsb + OFF_F2 + ly * 65536;
        const float* gv = ctx_g + ly * C_;
        const float* bv = ctx_b + ly * C_;

        // ---- xn = LN(x,1e-6) -> slot0 ----
        {
            float mo[4], io[4];
#pragma unroll
            for (int r = 0; r < 4; ++r) {
                float s = 0.f, ss = 0.f;
#pragma unroll
                for (int nt = 0; nt < 8; ++nt) { float v = xacc[nt][r]; s += v; ss += v * v; }
#pragma unroll
                for (int m = 1; m <= 8; m <<= 1) { s += __shfl_xor(s, m, 64); ss += __shfl_xor(ss, m, 64); }
                float mn = s * (1.f / 128.f);
                mo[r] = mn; io[r] = rsqrtf(ss * (1.f / 128.f) - mn * mn + 1e-6f);
            }
#pragma unroll
            for (int nt = 0; nt < 8; ++nt)
#pragma unroll
                for (int r = 0; r < 4; ++r)
                    arena[(4 * quad + r) * 136 + 16 * nt + cidx] =
                        f2bf((xacc[nt][r] - mo[r]) * io[r]);
        }
        __syncthreads();
        s8v a_xn[4];
#pragma unroll
        for (int kt = 0; kt < 4; ++kt)
            a_xn[kt] = *(const s8v*)(arena + cidx * 136 + kt * 32 + 8 * quad);

        // ---- build cn tiles (affine in regs) -> slots 1-4 ----
#pragma unroll 1
        for (int mt = 0; mt < 4; ++mt) {
            const u16* csrc = nrmb + cbase[mt] + 32 * quad;
            u16* drow = arena + (1 + mt) * SLOT + cidx * 136 + 32 * quad;
#pragma unroll
            for (int t = 0; t < 4; ++t) {
                s8v raw = *(const s8v*)(csrc + 8 * t);
                float4 g0 = *(const float4*)&gv[32 * quad + 8 * t];
                float4 g1 = *(const float4*)&gv[32 * quad + 8 * t + 4];
                float4 b0 = *(const float4*)&bv[32 * quad + 8 * t];
                float4 b1 = *(const float4*)&bv[32 * quad + 8 * t + 4];
                s8v o;
                o[0] = (short)f2bf(fmaf(bfu((u16)raw[0]), g0.x, b0.x));
                o[1] = (short)f2bf(fmaf(bfu((u16)raw[1]), g0.y, b0.y));
                o[2] = (short)f2bf(fmaf(bfu((u16)raw[2]), g0.z, b0.z));
                o[3] = (short)f2bf(fmaf(bfu((u16)raw[3]), g0.w, b0.w));
                o[4] = (short)f2bf(fmaf(bfu((u16)raw[4]), g1.x, b1.x));
                o[5] = (short)f2bf(fmaf(bfu((u16)raw[5]), g1.y, b1.y));
                o[6] = (short)f2bf(fmaf(bfu((u16)raw[6]), g1.z, b1.z));
                o[7] = (short)f2bf(fmaf(bfu((u16)raw[7]), g1.w, b1.w));
                *(s8v*)(drow + 8 * t) = o;
            }
        }

        // ---- q = xn @ Wq + qb -> slot0 bf16 (overwrites xn) ----
        {
            f4v qa[8];
#pragma unroll
            for (int nt = 0; nt < 8; ++nt) {
                float bvv = qb[ly * C_ + 16 * nt + cidx];
                f4v t = {bvv, bvv, bvv, bvv}; qa[nt] = t;
            }
#pragma unroll
            for (int kt = 0; kt < 4; ++kt)
#pragma unroll
                for (int nt = 0; nt < 8; ++nt) {
                    s8v w = *(const s8v*)(Wq + ((size_t)((kt * 8 + nt) * 64 + lane)) * 8);
                    qa[nt] = __builtin_amdgcn_mfma_f32_16x16x32_bf16(a_xn[kt], w, qa[nt], 0, 0, 0);
                }
#pragma unroll
            for (int nt = 0; nt < 8; ++nt)
#pragma unroll
                for (int r = 0; r < 4; ++r)
                    arena[(4 * quad + r) * 136 + 16 * nt + cidx] = f2bf(qa[nt][r]);
        }
        __syncthreads();

        // ---- cn A-frags -> regs (held through k and v) ----
        s8v a_cn[4][4];
#pragma unroll
        for (int kt = 0; kt < 4; ++kt)
#pragma unroll
            for (int mt = 0; mt < 4; ++mt)
                a_cn[kt][mt] = *(const s8v*)(arena + (1 + mt) * SLOT + cidx * 136 + kt * 32 + 8 * quad);

        // ---- k GEMM (frag-once) + fused raw scores -> s_at ----
#pragma unroll 1
        for (int h = 0; h < 4; ++h) {
            f4v ka[2][4];
#pragma unroll
            for (int ntp = 0; ntp < 2; ++ntp) {
                float kbb = kb[ly * C_ + 16 * (2 * h + ntp) + cidx];
#pragma unroll
                for (int mt = 0; mt < 4; ++mt) { f4v t = {kbb, kbb, kbb, kbb}; ka[ntp][mt] = t; }
            }
#pragma unroll
            for (int kt = 0; kt < 4; ++kt)
#pragma unroll
                for (int ntp = 0; ntp < 2; ++ntp) {
                    int nt = 2 * h + ntp;
                    s8v w = *(const s8v*)(Wk + ((size_t)((kt * 8 + nt) * 64 + lane)) * 8);
#pragma unroll
                    for (int mt = 0; mt < 4; ++mt)
                        ka[ntp][mt] = __builtin_amdgcn_mfma_f32_16x16x32_bf16(a_cn[kt][mt], w, ka[ntp][mt], 0, 0, 0);
                }
            float part[4][4];
#pragma unroll
            for (int mt = 0; mt < 4; ++mt)
#pragma unroll
                for (int r = 0; r < 4; ++r) part[mt][r] = 0.f;
#pragma unroll
            for (int ntp = 0; ntp < 2; ++ntp)
#pragma unroll
                for (int mt = 0; mt < 4; ++mt) {
                    float qv = bfu(arena[(4 * mt + quad) * 136 + 16 * (2 * h + ntp) + cidx]);
#pragma unroll
                    for (int r = 0; r < 4; ++r) part[mt][r] = fmaf(qv, ka[ntp][mt][r], part[mt][r]);
                }
#pragma unroll
            for (int mt = 0; mt < 4; ++mt)
#pragma unroll
                for (int r = 0; r < 4; ++r) {
#pragma unroll
                    for (int m = 1; m <= 8; m <<= 1) part[mt][r] += __shfl_xor(part[mt][r], m, 64);
                }
            if (cidx == 0) {
#pragma unroll
                for (int mt = 0; mt < 4; ++mt) {
                    float4 t = {part[mt][0], part[mt][1], part[mt][2], part[mt][3]};
                    *(float4*)&s_at[(4 * mt + quad) * 16 + 4 * h] = t;
                }
            }
        }
        __syncthreads();

        // ---- softmax in place ----
        {
            int p = lane >> 2, h = lane & 3;
            float4 sc = *(float4*)&s_at[p * 16 + 4 * h];
            int pw = wu0 + p;
            float sim[4] = {sc.x, sc.y, sc.z, sc.w};
#pragma unroll
            for (int r = 0; r < 4; ++r) {
                int rxv = min((pw >> 1) + (r & 1), WD_ - 1);
                float cd = ((r >> 1) ? dyv1 : dyv0) - (float)abs(pw - 2 * rxv);
                sim[r] = sim[r] * 0.17677669529663687f + slopes[h] * cd;
            }
            float mx = fmaxf(fmaxf(sim[0], sim[1]), fmaxf(sim[2], sim[3]));
            float e0 = __expf(sim[0] - mx), e1 = __expf(sim[1] - mx);
            float e2 = __expf(sim[2] - mx), e3 = __expf(sim[3] - mx);
            float si = 1.f / (e0 + e1 + e2 + e3);
            float4 at = {e0 * si, e1 * si, e2 * si, e3 * si};
            *(float4*)&s_at[p * 16 + 4 * h] = at;
        }
        __syncthreads();

        // ---- v GEMM (frag-once) + fused o = attn@v -> oT (slot1) ----
#pragma unroll 1
        for (int nt = 0; nt < 8; ++nt) {
            f4v va[4];
            float vbb = vb[ly * C_ + 16 * nt + cidx];
#pragma unroll
            for (int mt = 0; mt < 4; ++mt) { f4v t = {vbb, vbb, vbb, vbb}; va[mt] = t; }
#pragma unroll
            for (int kt = 0; kt < 4; ++kt) {
                s8v w = *(const s8v*)(Wv + ((size_t)((kt * 8 + nt) * 64 + lane)) * 8);
#pragma unroll
                for (int mt = 0; mt < 4; ++mt)
                    va[mt] = __builtin_amdgcn_mfma_f32_16x16x32_bf16(a_cn[kt][mt], w, va[mt], 0, 0, 0);
            }
            int h = nt >> 1;
#pragma unroll
            for (int mt = 0; mt < 4; ++mt) {
                float4 at = *(float4*)&s_at[(4 * mt + quad) * 16 + 4 * h];
                float ov = at.x * va[mt][0] + at.y * va[mt][1] + at.z * va[mt][2] + at.w * va[mt][3];
                arena[SLOT + (4 * mt + quad) * 136 + 16 * nt + cidx] = f2bf(ov);
            }
        }
        __syncthreads();

        // ---- x += o @ Wo + ob ----
        {
            s8v a_o[4];
#pragma unroll
            for (int kt = 0; kt < 4; ++kt)
                a_o[kt] = *(const s8v*)(arena + SLOT + cidx * 136 + kt * 32 + 8 * quad);
            f4v oa[8];
#pragma unroll
            for (int nt = 0; nt < 8; ++nt) {
                float bvv = ob[ly * C_ + 16 * nt + cidx];
                f4v t = {bvv, bvv, bvv, bvv}; oa[nt] = t;
            }
#pragma unroll
            for (int kt = 0; kt < 4; ++kt)
#pragma unroll
                for (int nt = 0; nt < 8; ++nt) {
                    s8v w = *(const s8v*)(Wo + ((size_t)((kt * 8 + nt) * 64 + lane)) * 8);
                    oa[nt] = __builtin_amdgcn_mfma_f32_16x16x32_bf16(a_o[kt], w, oa[nt], 0, 0, 0);
                }
#pragma unroll
            for (int nt = 0; nt < 8; ++nt)
#pragma unroll
                for (int r = 0; r < 4; ++r) xacc[nt][r] += oa[nt][r];
        }
        __syncthreads();

        // ---- hn = LN(x,1e-6) -> slot0 ----
        {
            float mo[4], io[4];
#pragma unroll
            for (int r = 0; r < 4; ++r) {
                float s = 0.f, ss = 0.f;
#pragma unroll
                for (int nt = 0; nt < 8; ++nt) { float v = xacc[nt][r]; s += v; ss += v * v; }
#pragma unroll
                for (int m = 1; m <= 8; m <<= 1) { s += __shfl_xor(s, m, 64); ss += __shfl_xor(ss, m, 64); }
                float mn = s * (1.f / 128.f);
                mo[r] = mn; io[r] = rsqrtf(ss * (1.f / 128.f) - mn * mn + 1e-6f);
            }
#pragma unroll
            for (int nt = 0; nt < 8; ++nt)
#pragma unroll
                for (int r = 0; r < 4; ++r)
                    arena[(4 * quad + r) * 136 + 16 * nt + cidx] =
                        f2bf((xacc[nt][r] - mo[r]) * io[r]);
        }
        __syncthreads();
        s8v a_hn[4];
#pragma unroll
        for (int kt = 0; kt < 4; ++kt)
            a_hn[kt] = *(const s8v*)(arena + cidx * 136 + kt * 32 + 8 * quad);
        __syncthreads();

        // ---- fc1 (128->512) + gelu_tanh -> sH ----
#pragma unroll 1
        for (int half = 0; half < 2; ++half) {
            f4v fa[16];
#pragma unroll
            for (int nt = 0; nt < 16; ++nt) {
                float bvv = f1b[ly * 512 + 16 * (half * 16 + nt) + cidx];
                f4v t = {bvv, bvv, bvv, bvv}; fa[nt] = t;
            }
#pragma unroll
            for (int kt = 0; kt < 4; ++kt)
#pragma unroll
                for (int nt = 0; nt < 16; ++nt) {
                    int ntg = half * 16 + nt;
                    s8v w = *(const s8v*)(W1 + ((size_t)((kt * 32 + ntg) * 64 + lane)) * 8);
                    fa[nt] = __builtin_amdgcn_mfma_f32_16x16x32_bf16(a_hn[kt], w, fa[nt], 0, 0, 0);
                }
#pragma unroll
            for (int nt = 0; nt < 16; ++nt)
#pragma unroll
                for (int r = 0; r < 4; ++r)
                    sH[(4 * quad + r) * 520 + 16 * (half * 16 + nt) + cidx] =
                        f2bf(gelu_tanh(fa[nt][r]));
        }
        __syncthreads();

        // ---- x += act @ W2 + f2b ----
        {
            f4v ga[8];
#pragma unroll
            for (int nt = 0; nt < 8; ++nt) {
                float bvv = f2b[ly * C_ + 16 * nt + cidx];
                f4v t = {bvv, bvv, bvv, bvv}; ga[nt] = t;
            }
            for (int kt = 0; kt < 16; ++kt) {
                s8v a = *(const s8v*)(sH + cidx * 520 + kt * 32 + 8 * quad);
#pragma unroll
                for (int nt = 0; nt < 8; ++nt) {
                    s8v w = *(const s8v*)(W2 + ((size_t)((kt * 8 + nt) * 64 + lane)) * 8);
                    ga[nt] = __builtin_amdgcn_mfma_f32_16x16x32_bf16(a, w, ga[nt], 0, 0, 0);
                }
            }
#pragma unroll
            for (int nt = 0; nt < 8; ++nt)
#pragma unroll
                for (int r = 0; r < 4; ++r) xacc[nt][r] += ga[nt][r];
        }
        __syncthreads();
    } // layer loop

    // ================= head =================
    {
        float mo[4], io[4];
#pragma unroll
        for (int r = 0; r < 4; ++r) {
            float s = 0.f, ss = 0.f;
#pragma unroll
            for (int nt = 0; nt < 8; ++nt) { float v = xacc[nt][r]; s += v; ss += v * v; }
#pragma unroll
            for (int m = 1; m <= 8; m <<= 1) { s += __shfl_xor(s, m, 64); ss += __shfl_xor(ss, m, 64); }
            float mn = s * (1.f / 128.f);
            mo[r] = mn; io[r] = rsqrtf(ss * (1.f / 128.f) - mn * mn + 1e-6f);
        }
#pragma unroll
        for (int nt = 0; nt < 8; ++nt)
#pragma unroll
            for (int r = 0; r < 4; ++r)
                arena[(4 * quad + r) * 136 + 16 * nt + cidx] =
                    f2bf((xacc[nt][r] - mo[r]) * io[r]);
    }
    __syncthreads();
    s8v a_xf[4];
#pragma unroll
    for (int kt = 0; kt < 4; ++kt)
        a_xf[kt] = *(const s8v*)(arena + cidx * 136 + kt * 32 + 8 * quad);

    // cf tiles (raw nrmb) -> slots 1-4
#pragma unroll 1
    for (int mt = 0; mt < 4; ++mt) {
        const u16* csrc = nrmb + cbase[mt] + 32 * quad;
        u16* drow = arena + (1 + mt) * SLOT + cidx * 136 + 32 * quad;
#pragma unroll
        for (int t = 0; t < 4; ++t)
            *(s8v*)(drow + 8 * t) = *(const s8v*)(csrc + 8 * t);
    }
    __syncthreads();

    const u16* Wxc = wsb + OFF_XC;
    const u16* Wcc = wsb + OFF_CC;
    float part[4][4];
#pragma unroll
    for (int mt = 0; mt < 4; ++mt)
#pragma unroll
        for (int r = 0; r < 4; ++r) part[mt][r] = 0.f;

#pragma unroll 1
    for (int ntc = 0; ntc < 4; ++ntc) {
        {
            f4v hx[6];
#pragma unroll
            for (int ntl = 0; ntl < 6; ++ntl) {
                float hb = o1b[16 * (6 * ntc + ntl) + cidx];
                f4v t = {hb, hb, hb, hb}; hx[ntl] = t;
            }
#pragma unroll
            for (int kt = 0; kt < 4; ++kt)
#pragma unroll
                for (int ntl = 0; ntl < 6; ++ntl) {
                    s8v w = *(const s8v*)(Wxc + ((size_t)((kt * 24 + 6 * ntc + ntl) * 64 + lane)) * 8);
                    hx[ntl] = __builtin_amdgcn_mfma_f32_16x16x32_bf16(a_xf[kt], w, hx[ntl], 0, 0, 0);
                }
#pragma unroll
            for (int ntl = 0; ntl < 6; ++ntl)
#pragma unroll
                for (int r = 0; r < 4; ++r)
                    arena[(4 * quad + r) * 100 + 16 * ntl + cidx] = f2bf(hx[ntl][r]);
        }
        __syncthreads();

        f4v hc[6][4];
#pragma unroll
        for (int ntl = 0; ntl < 6; ++ntl)
#pragma unroll
            for (int mt = 0; mt < 4; ++mt) { f4v t = {0.f, 0.f, 0.f, 0.f}; hc[ntl][mt] = t; }
#pragma unroll
        for (int kt = 0; kt < 4; ++kt) {
            s8v acf[4];
#pragma unroll
            for (int mt = 0; mt < 4; ++mt)
                acf[mt] = *(const s8v*)(arena + (1 + mt) * SLOT + cidx * 136 + kt * 32 + 8 * quad);
#pragma unroll
            for (int ntl = 0; ntl < 6; ++ntl) {
                s8v w = *(const s8v*)(Wcc + ((size_t)((kt * 24 + 6 * ntc + ntl) * 64 + lane)) * 8);
#pragma unroll
                for (int mt = 0; mt < 4; ++mt)
                    hc[ntl][mt] = __builtin_amdgcn_mfma_f32_16x16x32_bf16(acf[mt], w, hc[ntl][mt], 0, 0, 0);
            }
        }

#pragma unroll
        for (int ntl = 0; ntl < 6; ++ntl) {
            float w2v = o2w[16 * (6 * ntc + ntl) + cidx];
#pragma unroll
            for (int mt = 0; mt < 4; ++mt)
#pragma unroll
                for (int r = 0; r < 4; ++r) {
                    float h1 = hc[ntl][mt][r] +
                               bfu(arena[(4 * mt + quad) * 100 + 16 * ntl + cidx]);
                    part[mt][r] = fmaf(gelu_erf(h1), w2v, part[mt][r]);
                }
        }
        __syncthreads();
    }

#pragma unroll
    for (int mt = 0; mt < 4; ++mt)
#pragma unroll
        for (int r = 0; r < 4; ++r) {
#pragma unroll
            for (int m = 1; m <= 8; m <<= 1) part[mt][r] += __shfl_xor(part[mt][r], m, 64);
            part[mt][r] += o2b[0];
        }
    if (cidx == 0) {
#pragma unroll
        for (int mt = 0; mt < 4; ++mt) {
            float4 t = {part[mt][0], part[mt][1], part[mt][2], part[mt][3]};
            *(float4*)&s_rs[(4 * mt + quad) * 4] = t;
        }
    }
    __syncthreads();

    if (lane < 16) {
        int p = lane;
        float4 vv = *(float4*)&s_rs[4 * p];
        float mx = fmaxf(fmaxf(vv.x, vv.y), fmaxf(vv.z, vv.w));
        float e0 = __expf(vv.x - mx), e1 = __expf(vv.y - mx);
        float e2 = __expf(vv.z - mx), e3 = __expf(vv.w - mx);
        float si = 1.f / (e0 + e1 + e2 + e3);
        size_t base = ((size_t)(b * 4) * HU_ + hu) * WU_ + wu0 + p;
        out[base]                          = e0 * si;
        out[base + (size_t)HU_ * WU_]      = e1 * si;
        out[base + (size_t)2 * HU_ * WU_]  = e2 * si;
        out[base + (size_t)3 * HU_ * WU_]  = e3 * si;
    }
}

extern "C" void kernel_launch(void* const* d_in, const int* in_sizes, int n_in,
                              void* d_out, int out_size, void* d_ws, size_t ws_size,
                              hipStream_t stream) {
    const float* feat_map    = (const float*)d_in[0];
    const float* feat_map_up = (const float*)d_in[1];
    const float* ctx_ln_b    = (const float*)d_in[2];
    const float* q_w  = (const float*)d_in[3];
    const float* q_b  = (const float*)d_in[4];
    const float* k_w  = (const float*)d_in[5];
    const float* k_b  = (const float*)d_in[6];
    const float* v_w  = (const float*)d_in[7];
    const float* v_b  = (const float*)d_in[8];
    const float* o_w  = (const float*)d_in[9];
    const float* o_b  = (const float*)d_in[10];
    const float* fc1_w = (const float*)d_in[11];
    const float* fc1_b = (const float*)d_in[12];
    const float* fc2_w = (const float*)d_in[13];
    const float* fc2_b = (const float*)d_in[14];
    const float* out1_w = (const float*)d_in[15];
    const float* out1_b = (const float*)d_in[16];
    const float* out2_w = (const float*)d_in[17];
    const float* out2_b = (const float*)d_in[18];
    const float* ctx_ln_g = (const float*)d_in[19];
    float* out = (float*)d_out;
    u16* ws = (u16*)d_ws;

    swz_all<<<240, 256, 0, stream>>>(q_w, k_w, v_w, o_w, fc1_w, fc2_w, out1_w, ws);
    norm_kernel<<<128, 256, 0, stream>>>(feat_map, ws + OFF_NRM);

    fused_kernel<<<3072, 64, 0, stream>>>(
        ws + OFF_NRM, feat_map_up, ws, ctx_ln_g, ctx_ln_b,
        q_b, k_b, v_b, o_b, fc1_b, fc2_b,
        out1_b, out2_w, out2_b, out);
}